// Round 2
// baseline (1068.699 us; speedup 1.0000x reference)
//
#include <hip/hip_runtime.h>
#include <hip/hip_fp16.h>

constexpr int C = 128;
constexpr int N = 4096;
constexpr int B = 4;

typedef _Float16 f16x8 __attribute__((ext_vector_type(8)));
typedef _Float16 f16x4 __attribute__((ext_vector_type(4)));
typedef _Float16 f16x2 __attribute__((ext_vector_type(2)));
typedef float    f32x4 __attribute__((ext_vector_type(4)));

// ---------------------------------------------------------------------------
// Small GEMM: Y[b,o,n] = sum_c W[o,c] * X[b,c,n] (+bias[o]); O=128 fixed.
// grid (N/64, 2, B), block 256. fp32 compute; optional fp16 output.
// ---------------------------------------------------------------------------
template<bool BIAS, bool HALFOUT>
__global__ __launch_bounds__(256) void k_gw(const float* __restrict__ W,
                                            const float* __restrict__ X,
                                            const float* __restrict__ bias,
                                            void* __restrict__ Yv) {
  __shared__ float xs[128 * 64];
  __shared__ float wsh[128 * 65];   // stride 65: conflict-free staging writes
  const int tid = threadIdx.x;
  const int n0 = blockIdx.x * 64, o0 = blockIdx.y * 64, b = blockIdx.z;
  const float* Xb = X + (size_t)(b * C) * N + n0;
  // 128 rows x 64 cols = 2048 float4; 256 thr x 8 iters  (R1 fix: was 1/4 filled)
#pragma unroll
  for (int i = 0; i < 8; i++) {
    int idx = tid + i * 256;
    int c = idx >> 4, q = idx & 15;
    *(float4*)&xs[c * 64 + q * 4] = *(const float4*)&Xb[(size_t)c * N + q * 4];
  }
#pragma unroll
  for (int i = 0; i < 32; i++) {
    int idx = tid + i * 256;
    int c = idx & 127, o = idx >> 7;
    wsh[c * 65 + o] = W[(o0 + o) * C + c];
  }
  __syncthreads();
  const int to = tid >> 4, tn = tid & 15;
  float acc[4][4];
#pragma unroll
  for (int i = 0; i < 4; i++)
#pragma unroll
    for (int j = 0; j < 4; j++) acc[i][j] = 0.f;
#pragma unroll 4
  for (int c = 0; c < 128; c++) {
    const float4 x4 = *(const float4*)&xs[c * 64 + tn * 4];
    const float* wp = &wsh[c * 65 + to * 4];
    const float w0 = wp[0], w1 = wp[1], w2 = wp[2], w3 = wp[3];
    acc[0][0] += w0 * x4.x; acc[0][1] += w0 * x4.y; acc[0][2] += w0 * x4.z; acc[0][3] += w0 * x4.w;
    acc[1][0] += w1 * x4.x; acc[1][1] += w1 * x4.y; acc[1][2] += w1 * x4.z; acc[1][3] += w1 * x4.w;
    acc[2][0] += w2 * x4.x; acc[2][1] += w2 * x4.y; acc[2][2] += w2 * x4.z; acc[2][3] += w2 * x4.w;
    acc[3][0] += w3 * x4.x; acc[3][1] += w3 * x4.y; acc[3][2] += w3 * x4.z; acc[3][3] += w3 * x4.w;
  }
  const int ob = o0 + to * 4, nb = n0 + tn * 4;
#pragma unroll
  for (int i = 0; i < 4; i++) {
    const float bv_ = BIAS ? bias[ob + i] : 0.f;
    const float r0 = acc[i][0] + bv_, r1 = acc[i][1] + bv_, r2 = acc[i][2] + bv_, r3 = acc[i][3] + bv_;
    const size_t gi = (size_t)(b * C + ob + i) * N + nb;
    if (HALFOUT) {
      f16x4 h = {(_Float16)r0, (_Float16)r1, (_Float16)r2, (_Float16)r3};
      *(f16x4*)((_Float16*)Yv + gi) = h;
    } else {
      float4 r; r.x = r0; r.y = r1; r.z = r2; r.w = r3;
      *(float4*)((float*)Yv + gi) = r;
    }
  }
}

// ---------------------------------------------------------------------------
// QK projection with TRANSPOSED fp16 output: QT[b][n][o] (o<32), so that both
// MFMA operands of the energy Gram matmul are K-contiguous.
// grid (N/64, 1, B), block 256.
// ---------------------------------------------------------------------------
__global__ __launch_bounds__(256) void k_qkt(const float* __restrict__ W,
                                             const float* __restrict__ X,
                                             _Float16* __restrict__ QT) {
  __shared__ float xs[128 * 64];
  __shared__ float wsh[128 * 33];
  const int tid = threadIdx.x;
  const int n0 = blockIdx.x * 64, b = blockIdx.z;
  const float* Xb = X + (size_t)(b * C) * N + n0;
#pragma unroll
  for (int i = 0; i < 8; i++) {     // R1 fix: float4 staging, full 128 rows
    int idx = tid + i * 256;
    int c = idx >> 4, q = idx & 15;
    *(float4*)&xs[c * 64 + q * 4] = *(const float4*)&Xb[(size_t)c * N + q * 4];
  }
#pragma unroll
  for (int i = 0; i < 16; i++) {
    int idx = tid + i * 256;
    int c = idx & 127, o = idx >> 7;   // o in [0,32)
    wsh[c * 33 + o] = W[o * C + c];
  }
  __syncthreads();
  const int to = tid >> 4, tn = tid & 15;
  float acc[2][4];
#pragma unroll
  for (int i = 0; i < 2; i++)
#pragma unroll
    for (int j = 0; j < 4; j++) acc[i][j] = 0.f;
#pragma unroll 4
  for (int c = 0; c < 128; c++) {
    const float4 x4 = *(const float4*)&xs[c * 64 + tn * 4];
    const float w0 = wsh[c * 33 + to * 2], w1 = wsh[c * 33 + to * 2 + 1];
    acc[0][0] += w0 * x4.x; acc[0][1] += w0 * x4.y; acc[0][2] += w0 * x4.z; acc[0][3] += w0 * x4.w;
    acc[1][0] += w1 * x4.x; acc[1][1] += w1 * x4.y; acc[1][2] += w1 * x4.z; acc[1][3] += w1 * x4.w;
  }
  _Float16* Qb = QT + ((size_t)b * N + n0) * 32;
#pragma unroll
  for (int j = 0; j < 4; j++) {
    f16x2 h = {(_Float16)acc[0][j], (_Float16)acc[1][j]};
    *(f16x2*)&Qb[(tn * 4 + j) * 32 + to * 2] = h;
  }
}

// ---------------------------------------------------------------------------
// Energy Gram matrix via MFMA f16: E[bl,n,m] = sum_o QT[n][o]*QT[m][o].
// grid (N/64 m, N/64 n, bg), block 256 (4 waves; wave w owns n-sub w*16).
// ---------------------------------------------------------------------------
__global__ __launch_bounds__(256) void k_energy(const _Float16* __restrict__ QT,
                                                _Float16* __restrict__ E, int b0) {
  __shared__ _Float16 Qn[64 * 40];
  __shared__ _Float16 Qm[64 * 40];
  __shared__ _Float16 Ts[64 * 72];
  const int tid = threadIdx.x;
  const int m0 = blockIdx.x * 64, n0 = blockIdx.y * 64, bl = blockIdx.z, b = b0 + bl;
  const _Float16* Qb = QT + (size_t)b * N * 32;
#pragma unroll
  for (int i = 0; i < 2; i++) {
    int idx = tid + i * 256;            // 0..511
    int r = (idx >> 2) & 63, ch = idx & 3;
    int base = (idx >> 8) ? m0 : n0;
    _Float16* dst = (idx >> 8) ? Qm : Qn;
    *(f16x8*)&dst[r * 40 + ch * 8] = *(const f16x8*)&Qb[(size_t)(base + r) * 32 + ch * 8];
  }
  __syncthreads();
  const int w = tid >> 6, lane = tid & 63, quad = lane >> 4, lr = lane & 15;
  f32x4 acc[4];
#pragma unroll
  for (int mi = 0; mi < 4; mi++) acc[mi] = (f32x4){0.f, 0.f, 0.f, 0.f};
  const f16x8 aF = *(const f16x8*)&Qn[(w * 16 + lr) * 40 + quad * 8];
#pragma unroll
  for (int mi = 0; mi < 4; mi++) {
    const f16x8 bF = *(const f16x8*)&Qm[(mi * 16 + lr) * 40 + quad * 8];
    acc[mi] = __builtin_amdgcn_mfma_f32_16x16x32_f16(aF, bF, acc[mi], 0, 0, 0);
  }
#pragma unroll
  for (int mi = 0; mi < 4; mi++)
#pragma unroll
    for (int r = 0; r < 4; r++)
      Ts[(w * 16 + quad * 4 + r) * 72 + mi * 16 + lr] = (_Float16)acc[mi][r];
  __syncthreads();
#pragma unroll
  for (int i = 0; i < 2; i++) {
    int idx = tid + i * 256;
    int r = idx >> 3, ch = idx & 7;
    *(f16x8*)&E[((size_t)bl * N + n0 + r) * N + m0 + ch * 8] = *(const f16x8*)&Ts[r * 72 + ch * 8];
  }
}

// ---------------------------------------------------------------------------
// Row softmax stats (valid rows only): rowmax, 1/rowsum. grid (N, bg), 256 thr.
// ---------------------------------------------------------------------------
__global__ __launch_bounds__(256) void k_rs(const _Float16* __restrict__ E,
                                            const int* __restrict__ mask,
                                            float* __restrict__ rowmax,
                                            float* __restrict__ rowsi, int b0) {
  const int r = blockIdx.x, bl = blockIdx.y, b = b0 + bl, tid = threadIdx.x;
  if (mask[b * N + r] == 0) return;          // stats never read for invalid rows
  const _Float16* Er = E + ((size_t)bl * N + r) * N;
  const int* Mb = mask + b * N;
  float ev[16]; int va[16];
  float mx = -3.0e38f;
#pragma unroll
  for (int v = 0; v < 2; v++) {
    const int nb = (tid + v * 256) * 8;
    const f16x8 e8 = *(const f16x8*)&Er[nb];
    const int4 ma = *(const int4*)&Mb[nb];
    const int4 mb2 = *(const int4*)&Mb[nb + 4];
    const int ml[8] = {ma.x, ma.y, ma.z, ma.w, mb2.x, mb2.y, mb2.z, mb2.w};
#pragma unroll
    for (int j = 0; j < 8; j++) {
      const float e = (float)e8[j];
      ev[v * 8 + j] = e; va[v * 8 + j] = ml[j];
      if (ml[j] && e > mx) mx = e;
    }
  }
#pragma unroll
  for (int o = 32; o > 0; o >>= 1) mx = fmaxf(mx, __shfl_down(mx, o, 64));
  __shared__ float red[4], red2[4];
  if ((tid & 63) == 0) red[tid >> 6] = mx;
  __syncthreads();
  mx = fmaxf(fmaxf(red[0], red[1]), fmaxf(red[2], red[3]));
  float s = 0.f;
#pragma unroll
  for (int i = 0; i < 16; i++)
    if (va[i]) s += __expf(ev[i] - mx);
#pragma unroll
  for (int o = 32; o > 0; o >>= 1) s += __shfl_down(s, o, 64);
  if ((tid & 63) == 0) red2[tid >> 6] = s;
  __syncthreads();
  if (tid == 0) {
    s = red2[0] + red2[1] + red2[2] + red2[3];
    rowmax[b * N + r] = mx;
    rowsi[b * N + r] = 1.0f / s;
  }
}

// ---------------------------------------------------------------------------
// In-place: E[m][n] -> PT[m][n] = attn[n][m] (uses E symmetry), plus
// colsum[m] = sum_n attn[n][m]. grid (N/4, bg), 256 thr, 4 m-rows/block.
// ---------------------------------------------------------------------------
__global__ __launch_bounds__(256) void k_pc(_Float16* __restrict__ Ep,
                                            const int* __restrict__ mask,
                                            const float* __restrict__ rowmax,
                                            const float* __restrict__ rowsi,
                                            float* __restrict__ colsum, int b0) {
  __shared__ float rmS[4096];
  __shared__ float riS[4096];
  __shared__ unsigned char mkS[4096];
  __shared__ float red[4];
  const int tid = threadIdx.x, bl = blockIdx.y, b = b0 + bl, m0 = blockIdx.x * 4;
#pragma unroll
  for (int i = 0; i < 4; i++) {
    const int v = tid + i * 256;      // float4 slot
    *(float4*)&rmS[v * 4] = *(const float4*)&rowmax[b * N + v * 4];
    *(float4*)&riS[v * 4] = *(const float4*)&rowsi[b * N + v * 4];
    const int4 mk = *(const int4*)&mask[b * N + v * 4];
    uchar4 mc;
    mc.x = (unsigned char)(mk.x != 0); mc.y = (unsigned char)(mk.y != 0);
    mc.z = (unsigned char)(mk.z != 0); mc.w = (unsigned char)(mk.w != 0);
    *(uchar4*)&mkS[v * 4] = mc;
  }
  __syncthreads();
  for (int mi = 0; mi < 4; mi++) {
    const int m = m0 + mi;
    const bool cv = mkS[m] != 0;
    _Float16* Em = Ep + ((size_t)bl * N + m) * N;
    float cs = 0.f;
#pragma unroll
    for (int v = 0; v < 2; v++) {
      const int nb = (tid + v * 256) * 8;
      const f16x8 e8 = *(const f16x8*)&Em[nb];
      const uchar4 k0 = *(const uchar4*)&mkS[nb];
      const uchar4 k1 = *(const uchar4*)&mkS[nb + 4];
      const unsigned char mks[8] = {k0.x, k0.y, k0.z, k0.w, k1.x, k1.y, k1.z, k1.w};
      const float4 rm0 = *(const float4*)&rmS[nb], rm1 = *(const float4*)&rmS[nb + 4];
      const float4 ri0 = *(const float4*)&riS[nb], ri1 = *(const float4*)&riS[nb + 4];
      const float rm[8] = {rm0.x, rm0.y, rm0.z, rm0.w, rm1.x, rm1.y, rm1.z, rm1.w};
      const float ri[8] = {ri0.x, ri0.y, ri0.z, ri0.w, ri1.x, ri1.y, ri1.z, ri1.w};
      f16x8 p8;
#pragma unroll
      for (int j = 0; j < 8; j++) {
        float p;
        if (mks[j]) p = cv ? __expf((float)e8[j] - rm[j]) * ri[j] : 0.0f;
        else        p = 0.000244140625f;   // 1/4096: fully-masked row -> uniform
        cs += p;
        p8[j] = (_Float16)p;
      }
      *(f16x8*)&Em[nb] = p8;
    }
#pragma unroll
    for (int o = 32; o > 0; o >>= 1) cs += __shfl_down(cs, o, 64);
    __syncthreads();
    if ((tid & 63) == 0) red[tid >> 6] = cs;
    __syncthreads();
    if (tid == 0) colsum[b * N + m] = red[0] + red[1] + red[2] + red[3];
  }
}

// ---------------------------------------------------------------------------
// x_r GEMM (MFMA f16): acc[c,m] = sum_n XV[c,n] * PT[m,n];
// Td[b,c,m] = H[b,c,m] - acc/(1e-9 + colsum[b,m]).
// grid (N/64, bg), block 256 (4 waves; wave w owns c-rows [w*32,w*32+32)).
// ---------------------------------------------------------------------------
__global__ __launch_bounds__(256) void k_xr(const _Float16* __restrict__ XV,
                                            const _Float16* __restrict__ PT,
                                            const float* __restrict__ H,
                                            const float* __restrict__ colsum,
                                            float* __restrict__ Td, int b0) {
  __shared__ _Float16 As[128 * 40];
  __shared__ _Float16 Bs[64 * 40];
  const int tid = threadIdx.x;
  const int m0 = blockIdx.x * 64, bl = blockIdx.y, b = b0 + bl;
  const _Float16* Ab = XV + (size_t)(b * C) * N;
  const _Float16* Bb = PT + ((size_t)bl * N + m0) * N;
  const int w = tid >> 6, lane = tid & 63, quad = lane >> 4, lr = lane & 15;
  f32x4 acc[2][4];
#pragma unroll
  for (int ci = 0; ci < 2; ci++)
#pragma unroll
    for (int mi = 0; mi < 4; mi++) acc[ci][mi] = (f32x4){0.f, 0.f, 0.f, 0.f};
  for (int k0 = 0; k0 < N; k0 += 32) {
#pragma unroll
    for (int i = 0; i < 2; i++) {
      const int idx = tid + i * 256;     // 512 16B-vectors for A
      const int c = idx >> 2, ch = idx & 3;
      *(f16x8*)&As[c * 40 + ch * 8] = *(const f16x8*)&Ab[(size_t)c * N + k0 + ch * 8];
    }
    {
      const int mm = tid >> 2, ch = tid & 3;
      *(f16x8*)&Bs[mm * 40 + ch * 8] = *(const f16x8*)&Bb[(size_t)mm * N + k0 + ch * 8];
    }
    __syncthreads();
    f16x8 af[2], bf[4];
#pragma unroll
    for (int ci = 0; ci < 2; ci++)
      af[ci] = *(const f16x8*)&As[(w * 32 + ci * 16 + lr) * 40 + quad * 8];
#pragma unroll
    for (int mi = 0; mi < 4; mi++)
      bf[mi] = *(const f16x8*)&Bs[(mi * 16 + lr) * 40 + quad * 8];
#pragma unroll
    for (int ci = 0; ci < 2; ci++)
#pragma unroll
      for (int mi = 0; mi < 4; mi++)
        acc[ci][mi] = __builtin_amdgcn_mfma_f32_16x16x32_f16(af[ci], bf[mi], acc[ci][mi], 0, 0, 0);
    __syncthreads();
  }
#pragma unroll
  for (int mi = 0; mi < 4; mi++) {
    const int m = m0 + mi * 16 + lr;
    const float rdiv = 1.0f / (1e-9f + colsum[b * N + m]);
#pragma unroll
    for (int ci = 0; ci < 2; ci++) {
      const int cb = w * 32 + ci * 16 + quad * 4;
#pragma unroll
      for (int r = 0; r < 4; r++) {
        const size_t gi = (size_t)(b * C + cb + r) * N + m;
        Td[gi] = H[gi] - acc[ci][mi][r] * rdiv;
      }
    }
  }
}

// ---------------------------------------------------------------------------
// BatchNorm stats over (B,N) per channel -> scale/shift. grid (C), 256 thr.
// ---------------------------------------------------------------------------
__global__ __launch_bounds__(256) void k_bnstats(const float* __restrict__ X,
                                                 const float* __restrict__ gamma,
                                                 const float* __restrict__ beta,
                                                 float* __restrict__ ss) {
  const int c = blockIdx.x, tid = threadIdx.x;
  float s = 0.f, s2 = 0.f;
  const float* base = X + (size_t)c * N;
  for (int i = tid; i < B * N; i += 256) {
    const float v = base[(size_t)(i >> 12) * (C * N) + (i & (N - 1))];
    s += v; s2 += v * v;
  }
#pragma unroll
  for (int o = 32; o > 0; o >>= 1) { s += __shfl_down(s, o, 64); s2 += __shfl_down(s2, o, 64); }
  __shared__ float r1[4], r2[4];
  if ((tid & 63) == 0) { r1[tid >> 6] = s; r2[tid >> 6] = s2; }
  __syncthreads();
  if (tid == 0) {
    s = r1[0] + r1[1] + r1[2] + r1[3];
    s2 = r2[0] + r2[1] + r2[2] + r2[3];
    const float inv = 1.0f / (B * N);
    const float mean = s * inv;
    const float var = s2 * inv - mean * mean;   // biased, like torch BN
    const float sc = gamma[c] * rsqrtf(var + 1e-5f);
    ss[2 * c] = sc;
    ss[2 * c + 1] = beta[c] - mean * sc;
  }
}

// ---------------------------------------------------------------------------
// Apply BN+ReLU (+residual, +write output slice). grid 2048, 256 thr, float4.
// ---------------------------------------------------------------------------
template<bool RES>
__global__ __launch_bounds__(256) void k_apply(const float* __restrict__ T2,
                                               const float* __restrict__ ss,
                                               float* __restrict__ H,
                                               float* __restrict__ Out) {
  const int i = blockIdx.x * 256 + threadIdx.x;   // float4 index
  const int f = i * 4;
  const int c = (f >> 12) & 127;
  const float sc = ss[2 * c], sh = ss[2 * c + 1];
  const float4 t = *(const float4*)&T2[f];
  float4 r;
  r.x = fmaxf(t.x * sc + sh, 0.f);
  r.y = fmaxf(t.y * sc + sh, 0.f);
  r.z = fmaxf(t.z * sc + sh, 0.f);
  r.w = fmaxf(t.w * sc + sh, 0.f);
  if (RES) {
    const float4 h = *(const float4*)&H[f];
    r.x += h.x; r.y += h.y; r.z += h.z; r.w += h.w;
    *(float4*)&H[f] = r;
    const int b = f >> 19;                // f / (C*N)
    const int rem = f & (C * N - 1);      // c*N + n
    *(float4*)&Out[(size_t)b * (4 * C * N) + rem] = r;
  } else {
    *(float4*)&H[f] = r;
  }
}

// ---------------------------------------------------------------------------
extern "C" void kernel_launch(void* const* d_in, const int* in_sizes, int n_in,
                              void* d_out, int out_size, void* d_ws, size_t ws_size,
                              hipStream_t stream) {
  const float* x    = (const float*)d_in[0];
  const int*   mask = (const int*)  d_in[1];
  const float* w1   = (const float*)d_in[2];
  const float* g1   = (const float*)d_in[3];
  const float* b1   = (const float*)d_in[4];
  const float* w2   = (const float*)d_in[5];
  const float* g2   = (const float*)d_in[6];
  const float* b2   = (const float*)d_in[7];
  const float* wqk  = (const float*)d_in[8];
  const float* wv   = (const float*)d_in[9];
  const float* bv   = (const float*)d_in[10];
  const float* wt   = (const float*)d_in[11];
  const float* bt   = (const float*)d_in[12];
  const float* sg   = (const float*)d_in[13];
  const float* sb   = (const float*)d_in[14];
  float* out = (float*)d_out;

  char* p = (char*)d_ws;
  auto alloc = [&](size_t bytes) { char* r = p; p += (bytes + 255) & ~(size_t)255; return r; };
  float*    H      = (float*)   alloc((size_t)B * C * N * 4);
  float*    T2     = (float*)   alloc((size_t)B * C * N * 4);
  float*    Td     = (float*)   alloc((size_t)B * C * N * 4);
  _Float16* XQKT   = (_Float16*)alloc((size_t)B * N * 32 * 2);
  _Float16* XV     = (_Float16*)alloc((size_t)B * C * N * 2);
  float*    rowmax = (float*)   alloc((size_t)B * N * 4);
  float*    rowsi  = (float*)   alloc((size_t)B * N * 4);
  float*    colsum = (float*)   alloc((size_t)B * N * 4);
  float*    ss     = (float*)   alloc((size_t)C * 2 * 4);
  const size_t fixedEnd = (size_t)(p - (char*)d_ws);
  const size_t e1 = (size_t)N * (size_t)N * 2;
  const int bg = (ws_size >= fixedEnd + 4 * e1) ? 4 : 1;   // batches per E pass
  _Float16* E = (_Float16*)p;

  // ---- stem: two conv1d(+BN+ReLU) ----
  k_gw<false, false><<<dim3(64, 2, B), 256, 0, stream>>>(w1, x, nullptr, T2);
  k_bnstats<<<C, 256, 0, stream>>>(T2, g1, b1, ss);
  k_apply<false><<<2048, 256, 0, stream>>>(T2, ss, H, nullptr);
  k_gw<false, false><<<dim3(64, 2, B), 256, 0, stream>>>(w2, H, nullptr, T2);
  k_bnstats<<<C, 256, 0, stream>>>(T2, g2, b2, ss);
  k_apply<false><<<2048, 256, 0, stream>>>(T2, ss, H, nullptr);

  // ---- 4 chained offset-attention layers ----
  for (int L = 0; L < 4; L++) {
    k_qkt<<<dim3(64, 1, B), 256, 0, stream>>>(wqk + (size_t)L * 32 * C, H, XQKT);
    k_gw<true, true><<<dim3(64, 2, B), 256, 0, stream>>>(wv + (size_t)L * C * C, H, bv + L * C, XV);
    for (int b0 = 0; b0 < B; b0 += bg) {
      k_energy<<<dim3(64, 64, bg), 256, 0, stream>>>(XQKT, E, b0);
      k_rs<<<dim3(N, bg), 256, 0, stream>>>(E, mask, rowmax, rowsi, b0);
      k_pc<<<dim3(N / 4, bg), 256, 0, stream>>>(E, mask, rowmax, rowsi, colsum, b0);
      k_xr<<<dim3(64, bg), 256, 0, stream>>>(XV, E, H, colsum, Td, b0);
    }
    k_gw<true, false><<<dim3(64, 2, B), 256, 0, stream>>>(wt + (size_t)L * C * C, Td, bt + L * C, T2);
    k_bnstats<<<C, 256, 0, stream>>>(T2, sg + L * C, sb + L * C, ss);
    k_apply<true><<<2048, 256, 0, stream>>>(T2, ss, H, out + (size_t)L * C * N);
  }
}

// Round 3
// 948.749 us; speedup vs baseline: 1.1264x; 1.1264x over previous
//
#include <hip/hip_runtime.h>
#include <hip/hip_fp16.h>

constexpr int C = 128;
constexpr int N = 4096;
constexpr int B = 4;

typedef _Float16 f16x8 __attribute__((ext_vector_type(8)));
typedef _Float16 f16x4 __attribute__((ext_vector_type(4)));
typedef _Float16 f16x2 __attribute__((ext_vector_type(2)));
typedef float    f32x4 __attribute__((ext_vector_type(4)));

// ---------------------------------------------------------------------------
// Small GEMM: Y[b,o,n] = sum_c W[o,c] * X[b,c,n] (+bias[o]); O=128 fixed.
// grid (N/64, 2, B), block 256. fp32 compute; optional fp16 output.
// ---------------------------------------------------------------------------
template<bool BIAS, bool HALFOUT>
__global__ __launch_bounds__(256) void k_gw(const float* __restrict__ W,
                                            const float* __restrict__ X,
                                            const float* __restrict__ bias,
                                            void* __restrict__ Yv) {
  __shared__ float xs[128 * 64];
  __shared__ float wsh[128 * 65];   // stride 65: conflict-free staging writes
  const int tid = threadIdx.x;
  const int n0 = blockIdx.x * 64, o0 = blockIdx.y * 64, b = blockIdx.z;
  const float* Xb = X + (size_t)(b * C) * N + n0;
#pragma unroll
  for (int i = 0; i < 8; i++) {
    int idx = tid + i * 256;
    int c = idx >> 4, q = idx & 15;
    *(float4*)&xs[c * 64 + q * 4] = *(const float4*)&Xb[(size_t)c * N + q * 4];
  }
#pragma unroll
  for (int i = 0; i < 32; i++) {
    int idx = tid + i * 256;
    int c = idx & 127, o = idx >> 7;
    wsh[c * 65 + o] = W[(o0 + o) * C + c];
  }
  __syncthreads();
  const int to = tid >> 4, tn = tid & 15;
  float acc[4][4];
#pragma unroll
  for (int i = 0; i < 4; i++)
#pragma unroll
    for (int j = 0; j < 4; j++) acc[i][j] = 0.f;
#pragma unroll 4
  for (int c = 0; c < 128; c++) {
    const float4 x4 = *(const float4*)&xs[c * 64 + tn * 4];
    const float* wp = &wsh[c * 65 + to * 4];
    const float w0 = wp[0], w1 = wp[1], w2 = wp[2], w3 = wp[3];
    acc[0][0] += w0 * x4.x; acc[0][1] += w0 * x4.y; acc[0][2] += w0 * x4.z; acc[0][3] += w0 * x4.w;
    acc[1][0] += w1 * x4.x; acc[1][1] += w1 * x4.y; acc[1][2] += w1 * x4.z; acc[1][3] += w1 * x4.w;
    acc[2][0] += w2 * x4.x; acc[2][1] += w2 * x4.y; acc[2][2] += w2 * x4.z; acc[2][3] += w2 * x4.w;
    acc[3][0] += w3 * x4.x; acc[3][1] += w3 * x4.y; acc[3][2] += w3 * x4.z; acc[3][3] += w3 * x4.w;
  }
  const int ob = o0 + to * 4, nb = n0 + tn * 4;
#pragma unroll
  for (int i = 0; i < 4; i++) {
    const float bv_ = BIAS ? bias[ob + i] : 0.f;
    const float r0 = acc[i][0] + bv_, r1 = acc[i][1] + bv_, r2 = acc[i][2] + bv_, r3 = acc[i][3] + bv_;
    const size_t gi = (size_t)(b * C + ob + i) * N + nb;
    if (HALFOUT) {
      f16x4 h = {(_Float16)r0, (_Float16)r1, (_Float16)r2, (_Float16)r3};
      *(f16x4*)((_Float16*)Yv + gi) = h;
    } else {
      float4 r; r.x = r0; r.y = r1; r.z = r2; r.w = r3;
      *(float4*)((float*)Yv + gi) = r;
    }
  }
}

// ---------------------------------------------------------------------------
// QK projection with TRANSPOSED fp16 output: QT[b][n][o] (o<32).
// grid (N/64, 1, B), block 256.
// ---------------------------------------------------------------------------
__global__ __launch_bounds__(256) void k_qkt(const float* __restrict__ W,
                                             const float* __restrict__ X,
                                             _Float16* __restrict__ QT) {
  __shared__ float xs[128 * 64];
  __shared__ float wsh[128 * 33];
  const int tid = threadIdx.x;
  const int n0 = blockIdx.x * 64, b = blockIdx.z;
  const float* Xb = X + (size_t)(b * C) * N + n0;
#pragma unroll
  for (int i = 0; i < 8; i++) {
    int idx = tid + i * 256;
    int c = idx >> 4, q = idx & 15;
    *(float4*)&xs[c * 64 + q * 4] = *(const float4*)&Xb[(size_t)c * N + q * 4];
  }
#pragma unroll
  for (int i = 0; i < 16; i++) {
    int idx = tid + i * 256;
    int c = idx & 127, o = idx >> 7;   // o in [0,32)
    wsh[c * 33 + o] = W[o * C + c];
  }
  __syncthreads();
  const int to = tid >> 4, tn = tid & 15;
  float acc[2][4];
#pragma unroll
  for (int i = 0; i < 2; i++)
#pragma unroll
    for (int j = 0; j < 4; j++) acc[i][j] = 0.f;
#pragma unroll 4
  for (int c = 0; c < 128; c++) {
    const float4 x4 = *(const float4*)&xs[c * 64 + tn * 4];
    const float w0 = wsh[c * 33 + to * 2], w1 = wsh[c * 33 + to * 2 + 1];
    acc[0][0] += w0 * x4.x; acc[0][1] += w0 * x4.y; acc[0][2] += w0 * x4.z; acc[0][3] += w0 * x4.w;
    acc[1][0] += w1 * x4.x; acc[1][1] += w1 * x4.y; acc[1][2] += w1 * x4.z; acc[1][3] += w1 * x4.w;
  }
  _Float16* Qb = QT + ((size_t)b * N + n0) * 32;
#pragma unroll
  for (int j = 0; j < 4; j++) {
    f16x2 h = {(_Float16)acc[0][j], (_Float16)acc[1][j]};
    *(f16x2*)&Qb[(tn * 4 + j) * 32 + to * 2] = h;
  }
}

// ---------------------------------------------------------------------------
// Energy Gram matrix via MFMA f16: E[bl,n,m] = sum_o QT[n][o]*QT[m][o].
// grid (N/64 m, N/64 n, bg), block 256.
// ---------------------------------------------------------------------------
__global__ __launch_bounds__(256) void k_energy(const _Float16* __restrict__ QT,
                                                _Float16* __restrict__ E, int b0) {
  __shared__ _Float16 Qn[64 * 40];
  __shared__ _Float16 Qm[64 * 40];
  __shared__ _Float16 Ts[64 * 72];
  const int tid = threadIdx.x;
  const int m0 = blockIdx.x * 64, n0 = blockIdx.y * 64, bl = blockIdx.z, b = b0 + bl;
  const _Float16* Qb = QT + (size_t)b * N * 32;
#pragma unroll
  for (int i = 0; i < 2; i++) {
    int idx = tid + i * 256;            // 0..511
    int r = (idx >> 2) & 63, ch = idx & 3;
    int base = (idx >> 8) ? m0 : n0;
    _Float16* dst = (idx >> 8) ? Qm : Qn;
    *(f16x8*)&dst[r * 40 + ch * 8] = *(const f16x8*)&Qb[(size_t)(base + r) * 32 + ch * 8];
  }
  __syncthreads();
  const int w = tid >> 6, lane = tid & 63, quad = lane >> 4, lr = lane & 15;
  f32x4 acc[4];
#pragma unroll
  for (int mi = 0; mi < 4; mi++) acc[mi] = (f32x4){0.f, 0.f, 0.f, 0.f};
  const f16x8 aF = *(const f16x8*)&Qn[(w * 16 + lr) * 40 + quad * 8];
#pragma unroll
  for (int mi = 0; mi < 4; mi++) {
    const f16x8 bF = *(const f16x8*)&Qm[(mi * 16 + lr) * 40 + quad * 8];
    acc[mi] = __builtin_amdgcn_mfma_f32_16x16x32_f16(aF, bF, acc[mi], 0, 0, 0);
  }
#pragma unroll
  for (int mi = 0; mi < 4; mi++)
#pragma unroll
    for (int r = 0; r < 4; r++)
      Ts[(w * 16 + quad * 4 + r) * 72 + mi * 16 + lr] = (_Float16)acc[mi][r];
  __syncthreads();
#pragma unroll
  for (int i = 0; i < 2; i++) {
    int idx = tid + i * 256;
    int r = idx >> 3, ch = idx & 7;
    *(f16x8*)&E[((size_t)bl * N + n0 + r) * N + m0 + ch * 8] = *(const f16x8*)&Ts[r * 72 + ch * 8];
  }
}

// ---------------------------------------------------------------------------
// Row softmax stats for ALL rows. Valid: rm=max, ri=1/sum (ri >= 1/4096 > 0).
// Invalid row: rm=1e30, ri=0  (consumer decodes ri==0 -> P = 1/4096).
// grid (N, bg), 256 thr.
// ---------------------------------------------------------------------------
__global__ __launch_bounds__(256) void k_rs(const _Float16* __restrict__ E,
                                            const int* __restrict__ mask,
                                            float* __restrict__ rowmax,
                                            float* __restrict__ rowsi, int b0) {
  const int r = blockIdx.x, bl = blockIdx.y, b = b0 + bl, tid = threadIdx.x;
  if (mask[b * N + r] == 0) {
    if (tid == 0) { rowmax[b * N + r] = 1e30f; rowsi[b * N + r] = 0.0f; }
    return;
  }
  const _Float16* Er = E + ((size_t)bl * N + r) * N;
  const int* Mb = mask + b * N;
  float ev[16]; int va[16];
  float mx = -3.0e38f;
#pragma unroll
  for (int v = 0; v < 2; v++) {
    const int nb = (tid + v * 256) * 8;
    const f16x8 e8 = *(const f16x8*)&Er[nb];
    const int4 ma = *(const int4*)&Mb[nb];
    const int4 mb2 = *(const int4*)&Mb[nb + 4];
    const int ml[8] = {ma.x, ma.y, ma.z, ma.w, mb2.x, mb2.y, mb2.z, mb2.w};
#pragma unroll
    for (int j = 0; j < 8; j++) {
      const float e = (float)e8[j];
      ev[v * 8 + j] = e; va[v * 8 + j] = ml[j];
      if (ml[j] && e > mx) mx = e;
    }
  }
#pragma unroll
  for (int o = 32; o > 0; o >>= 1) mx = fmaxf(mx, __shfl_down(mx, o, 64));
  __shared__ float red[4], red2[4];
  if ((tid & 63) == 0) red[tid >> 6] = mx;
  __syncthreads();
  mx = fmaxf(fmaxf(red[0], red[1]), fmaxf(red[2], red[3]));
  float s = 0.f;
#pragma unroll
  for (int i = 0; i < 16; i++)
    if (va[i]) s += __expf(ev[i] - mx);
#pragma unroll
  for (int o = 32; o > 0; o >>= 1) s += __shfl_down(s, o, 64);
  if ((tid & 63) == 0) red2[tid >> 6] = s;
  __syncthreads();
  if (tid == 0) {
    s = red2[0] + red2[1] + red2[2] + red2[3];
    rowmax[b * N + r] = mx;
    rowsi[b * N + r] = 1.0f / s;
  }
}

// ---------------------------------------------------------------------------
// Fused P-transform + x_r GEMM (R2: absorbs old k_pc).
// B-staging computes PT[m][n] = vm * exp(E[m][n]-rm[n]) * ri[n]  (ri==0 ->
// fully-masked row n -> 1/4096) on the fly, accumulating colsum[m] in-reg.
// acc[c,m] = sum_n XV[c,n] * PT[m,n]; Td = H - acc/(1e-9+colsum).
// grid (N/64, bg), block 256 (4 waves; wave w owns c-rows [w*32,w*32+32)).
// ---------------------------------------------------------------------------
__global__ __launch_bounds__(256) void k_xr(const _Float16* __restrict__ XV,
                                            const _Float16* __restrict__ E,
                                            const float* __restrict__ H,
                                            const int* __restrict__ mask,
                                            const float* __restrict__ rowmax,
                                            const float* __restrict__ rowsi,
                                            float* __restrict__ Td, int b0) {
  __shared__ _Float16 As[128 * 40];
  __shared__ _Float16 Bs[64 * 40];
  __shared__ float colS[64];
  const int tid = threadIdx.x;
  const int m0 = blockIdx.x * 64, bl = blockIdx.y, b = b0 + bl;
  const _Float16* Ab = XV + (size_t)(b * C) * N;
  const _Float16* Eb = E + ((size_t)bl * N + m0) * N;
  const int mB = tid >> 2, chB = tid & 3;     // B-staging assignment (fixed m)
  const float vm = (mask[b * N + m0 + mB] != 0) ? 1.0f : 0.0f;
  const float* rmB = rowmax + b * N;
  const float* riB = rowsi + b * N;
  const int w = tid >> 6, lane = tid & 63, quad = lane >> 4, lr = lane & 15;
  float cs = 0.f;
  f32x4 acc[2][4];
#pragma unroll
  for (int ci = 0; ci < 2; ci++)
#pragma unroll
    for (int mi = 0; mi < 4; mi++) acc[ci][mi] = (f32x4){0.f, 0.f, 0.f, 0.f};
  for (int k0 = 0; k0 < N; k0 += 32) {
#pragma unroll
    for (int i = 0; i < 2; i++) {
      const int idx = tid + i * 256;     // 512 16B-vectors for A
      const int c = idx >> 2, ch = idx & 3;
      *(f16x8*)&As[c * 40 + ch * 8] = *(const f16x8*)&Ab[(size_t)c * N + k0 + ch * 8];
    }
    {
      const int nb = k0 + chB * 8;
      const f16x8 e8 = *(const f16x8*)&Eb[(size_t)mB * N + nb];
      const float4 rm0 = *(const float4*)&rmB[nb], rm1 = *(const float4*)&rmB[nb + 4];
      const float4 ri0 = *(const float4*)&riB[nb], ri1 = *(const float4*)&riB[nb + 4];
      const float rmv[8] = {rm0.x, rm0.y, rm0.z, rm0.w, rm1.x, rm1.y, rm1.z, rm1.w};
      const float riv[8] = {ri0.x, ri0.y, ri0.z, ri0.w, ri1.x, ri1.y, ri1.z, ri1.w};
      f16x8 p8;
#pragma unroll
      for (int j = 0; j < 8; j++) {
        const float base = vm * __expf((float)e8[j] - rmv[j]) * riv[j];
        const float p = (riv[j] == 0.0f) ? 0.000244140625f : base;  // 1/4096
        cs += p;
        p8[j] = (_Float16)p;
      }
      *(f16x8*)&Bs[mB * 40 + chB * 8] = p8;
    }
    __syncthreads();
    f16x8 af[2], bf[4];
#pragma unroll
    for (int ci = 0; ci < 2; ci++)
      af[ci] = *(const f16x8*)&As[(w * 32 + ci * 16 + lr) * 40 + quad * 8];
#pragma unroll
    for (int mi = 0; mi < 4; mi++)
      bf[mi] = *(const f16x8*)&Bs[(mi * 16 + lr) * 40 + quad * 8];
#pragma unroll
    for (int ci = 0; ci < 2; ci++)
#pragma unroll
      for (int mi = 0; mi < 4; mi++)
        acc[ci][mi] = __builtin_amdgcn_mfma_f32_16x16x32_f16(af[ci], bf[mi], acc[ci][mi], 0, 0, 0);
    __syncthreads();
  }
  // colsum: threads 4m..4m+3 (same wave) hold partial sums for local row m
  cs += __shfl_down(cs, 1, 64);
  cs += __shfl_down(cs, 2, 64);
  if ((tid & 3) == 0) colS[mB] = cs;
  __syncthreads();
#pragma unroll
  for (int mi = 0; mi < 4; mi++) {
    const int ml = mi * 16 + lr;
    const int m = m0 + ml;
    const float rdiv = 1.0f / (1e-9f + colS[ml]);
#pragma unroll
    for (int ci = 0; ci < 2; ci++) {
      const int cb = w * 32 + ci * 16 + quad * 4;
#pragma unroll
      for (int r = 0; r < 4; r++) {
        const size_t gi = (size_t)(b * C + cb + r) * N + m;
        Td[gi] = H[gi] - acc[ci][mi][r] * rdiv;
      }
    }
  }
}

// ---------------------------------------------------------------------------
// BatchNorm stats over (B,N) per channel -> scale/shift. grid (C), 256 thr.
// ---------------------------------------------------------------------------
__global__ __launch_bounds__(256) void k_bnstats(const float* __restrict__ X,
                                                 const float* __restrict__ gamma,
                                                 const float* __restrict__ beta,
                                                 float* __restrict__ ss) {
  const int c = blockIdx.x, tid = threadIdx.x;
  float s = 0.f, s2 = 0.f;
  const float* base = X + (size_t)c * N;
  for (int i = tid; i < B * N; i += 256) {
    const float v = base[(size_t)(i >> 12) * (C * N) + (i & (N - 1))];
    s += v; s2 += v * v;
  }
#pragma unroll
  for (int o = 32; o > 0; o >>= 1) { s += __shfl_down(s, o, 64); s2 += __shfl_down(s2, o, 64); }
  __shared__ float r1[4], r2[4];
  if ((tid & 63) == 0) { r1[tid >> 6] = s; r2[tid >> 6] = s2; }
  __syncthreads();
  if (tid == 0) {
    s = r1[0] + r1[1] + r1[2] + r1[3];
    s2 = r2[0] + r2[1] + r2[2] + r2[3];
    const float inv = 1.0f / (B * N);
    const float mean = s * inv;
    const float var = s2 * inv - mean * mean;   // biased, like torch BN
    const float sc = gamma[c] * rsqrtf(var + 1e-5f);
    ss[2 * c] = sc;
    ss[2 * c + 1] = beta[c] - mean * sc;
  }
}

// ---------------------------------------------------------------------------
// Apply BN+ReLU (+residual, +write output slice). grid 2048, 256 thr, float4.
// ---------------------------------------------------------------------------
template<bool RES>
__global__ __launch_bounds__(256) void k_apply(const float* __restrict__ T2,
                                               const float* __restrict__ ss,
                                               float* __restrict__ H,
                                               float* __restrict__ Out) {
  const int i = blockIdx.x * 256 + threadIdx.x;   // float4 index
  const int f = i * 4;
  const int c = (f >> 12) & 127;
  const float sc = ss[2 * c], sh = ss[2 * c + 1];
  const float4 t = *(const float4*)&T2[f];
  float4 r;
  r.x = fmaxf(t.x * sc + sh, 0.f);
  r.y = fmaxf(t.y * sc + sh, 0.f);
  r.z = fmaxf(t.z * sc + sh, 0.f);
  r.w = fmaxf(t.w * sc + sh, 0.f);
  if (RES) {
    const float4 h = *(const float4*)&H[f];
    r.x += h.x; r.y += h.y; r.z += h.z; r.w += h.w;
    *(float4*)&H[f] = r;
    const int b = f >> 19;                // f / (C*N)
    const int rem = f & (C * N - 1);      // c*N + n
    *(float4*)&Out[(size_t)b * (4 * C * N) + rem] = r;
  } else {
    *(float4*)&H[f] = r;
  }
}

// ---------------------------------------------------------------------------
extern "C" void kernel_launch(void* const* d_in, const int* in_sizes, int n_in,
                              void* d_out, int out_size, void* d_ws, size_t ws_size,
                              hipStream_t stream) {
  const float* x    = (const float*)d_in[0];
  const int*   mask = (const int*)  d_in[1];
  const float* w1   = (const float*)d_in[2];
  const float* g1   = (const float*)d_in[3];
  const float* b1   = (const float*)d_in[4];
  const float* w2   = (const float*)d_in[5];
  const float* g2   = (const float*)d_in[6];
  const float* b2   = (const float*)d_in[7];
  const float* wqk  = (const float*)d_in[8];
  const float* wv   = (const float*)d_in[9];
  const float* bv   = (const float*)d_in[10];
  const float* wt   = (const float*)d_in[11];
  const float* bt   = (const float*)d_in[12];
  const float* sg   = (const float*)d_in[13];
  const float* sb   = (const float*)d_in[14];
  float* out = (float*)d_out;

  char* p = (char*)d_ws;
  auto alloc = [&](size_t bytes) { char* r = p; p += (bytes + 255) & ~(size_t)255; return r; };
  float*    H      = (float*)   alloc((size_t)B * C * N * 4);
  float*    T2     = (float*)   alloc((size_t)B * C * N * 4);
  float*    Td     = (float*)   alloc((size_t)B * C * N * 4);
  _Float16* XQKT   = (_Float16*)alloc((size_t)B * N * 32 * 2);
  _Float16* XV     = (_Float16*)alloc((size_t)B * C * N * 2);
  float*    rowmax = (float*)   alloc((size_t)B * N * 4);
  float*    rowsi  = (float*)   alloc((size_t)B * N * 4);
  float*    ss     = (float*)   alloc((size_t)C * 2 * 4);
  const size_t fixedEnd = (size_t)(p - (char*)d_ws);
  const size_t e1 = (size_t)N * (size_t)N * 2;
  const int bg = (ws_size >= fixedEnd + 4 * e1) ? 4 : 1;   // batches per E pass
  _Float16* E = (_Float16*)p;

  // ---- stem: two conv1d(+BN+ReLU) ----
  k_gw<false, false><<<dim3(64, 2, B), 256, 0, stream>>>(w1, x, nullptr, T2);
  k_bnstats<<<C, 256, 0, stream>>>(T2, g1, b1, ss);
  k_apply<false><<<2048, 256, 0, stream>>>(T2, ss, H, nullptr);
  k_gw<false, false><<<dim3(64, 2, B), 256, 0, stream>>>(w2, H, nullptr, T2);
  k_bnstats<<<C, 256, 0, stream>>>(T2, g2, b2, ss);
  k_apply<false><<<2048, 256, 0, stream>>>(T2, ss, H, nullptr);

  // ---- 4 chained offset-attention layers ----
  for (int L = 0; L < 4; L++) {
    k_qkt<<<dim3(64, 1, B), 256, 0, stream>>>(wqk + (size_t)L * 32 * C, H, XQKT);
    k_gw<true, true><<<dim3(64, 2, B), 256, 0, stream>>>(wv + (size_t)L * C * C, H, bv + L * C, XV);
    for (int b0 = 0; b0 < B; b0 += bg) {
      k_energy<<<dim3(64, 64, bg), 256, 0, stream>>>(XQKT, E, b0);
      k_rs<<<dim3(N, bg), 256, 0, stream>>>(E, mask, rowmax, rowsi, b0);
      k_xr<<<dim3(64, bg), 256, 0, stream>>>(XV, E, H, mask, rowmax, rowsi, Td, b0);
    }
    k_gw<true, false><<<dim3(64, 2, B), 256, 0, stream>>>(wt + (size_t)L * C * C, Td, bt + L * C, T2);
    k_bnstats<<<C, 256, 0, stream>>>(T2, sg + L * C, sb + L * C, ss);
    k_apply<true><<<2048, 256, 0, stream>>>(T2, ss, H, out + (size_t)L * C * N);
  }
}

// Round 4
// 903.136 us; speedup vs baseline: 1.1833x; 1.0505x over previous
//
#include <hip/hip_runtime.h>
#include <hip/hip_fp16.h>

constexpr int C = 128;
constexpr int N = 4096;
constexpr int B = 4;

typedef _Float16 f16x8 __attribute__((ext_vector_type(8)));
typedef _Float16 f16x4 __attribute__((ext_vector_type(4)));
typedef _Float16 f16x2 __attribute__((ext_vector_type(2)));
typedef float    f32x4 __attribute__((ext_vector_type(4)));

// ---------------------------------------------------------------------------
// Small GEMM: Y[b,o,n] = sum_c W[o,c] * X[b,c,n] (+bias[o]); O=128 fixed.
// grid (N/64, 2, B), block 256. fp32 compute; optional fp16 output.
// ---------------------------------------------------------------------------
template<bool BIAS, bool HALFOUT>
__global__ __launch_bounds__(256) void k_gw(const float* __restrict__ W,
                                            const float* __restrict__ X,
                                            const float* __restrict__ bias,
                                            void* __restrict__ Yv) {
  __shared__ float xs[128 * 64];
  __shared__ float wsh[128 * 65];   // stride 65: conflict-free staging writes
  const int tid = threadIdx.x;
  const int n0 = blockIdx.x * 64, o0 = blockIdx.y * 64, b = blockIdx.z;
  const float* Xb = X + (size_t)(b * C) * N + n0;
#pragma unroll
  for (int i = 0; i < 8; i++) {
    int idx = tid + i * 256;
    int c = idx >> 4, q = idx & 15;
    *(float4*)&xs[c * 64 + q * 4] = *(const float4*)&Xb[(size_t)c * N + q * 4];
  }
#pragma unroll
  for (int i = 0; i < 32; i++) {
    int idx = tid + i * 256;
    int c = idx & 127, o = idx >> 7;
    wsh[c * 65 + o] = W[(o0 + o) * C + c];
  }
  __syncthreads();
  const int to = tid >> 4, tn = tid & 15;
  float acc[4][4];
#pragma unroll
  for (int i = 0; i < 4; i++)
#pragma unroll
    for (int j = 0; j < 4; j++) acc[i][j] = 0.f;
#pragma unroll 4
  for (int c = 0; c < 128; c++) {
    const float4 x4 = *(const float4*)&xs[c * 64 + tn * 4];
    const float* wp = &wsh[c * 65 + to * 4];
    const float w0 = wp[0], w1 = wp[1], w2 = wp[2], w3 = wp[3];
    acc[0][0] += w0 * x4.x; acc[0][1] += w0 * x4.y; acc[0][2] += w0 * x4.z; acc[0][3] += w0 * x4.w;
    acc[1][0] += w1 * x4.x; acc[1][1] += w1 * x4.y; acc[1][2] += w1 * x4.z; acc[1][3] += w1 * x4.w;
    acc[2][0] += w2 * x4.x; acc[2][1] += w2 * x4.y; acc[2][2] += w2 * x4.z; acc[2][3] += w2 * x4.w;
    acc[3][0] += w3 * x4.x; acc[3][1] += w3 * x4.y; acc[3][2] += w3 * x4.z; acc[3][3] += w3 * x4.w;
  }
  const int ob = o0 + to * 4, nb = n0 + tn * 4;
#pragma unroll
  for (int i = 0; i < 4; i++) {
    const float bv_ = BIAS ? bias[ob + i] : 0.f;
    const float r0 = acc[i][0] + bv_, r1 = acc[i][1] + bv_, r2 = acc[i][2] + bv_, r3 = acc[i][3] + bv_;
    const size_t gi = (size_t)(b * C + ob + i) * N + nb;
    if (HALFOUT) {
      f16x4 h = {(_Float16)r0, (_Float16)r1, (_Float16)r2, (_Float16)r3};
      *(f16x4*)((_Float16*)Yv + gi) = h;
    } else {
      float4 r; r.x = r0; r.y = r1; r.z = r2; r.w = r3;
      *(float4*)((float*)Yv + gi) = r;
    }
  }
}

// ---------------------------------------------------------------------------
// QK projection with TRANSPOSED fp16 output: QT[b][n][o] (o<32).
// grid (N/64, 1, B), block 256.
// ---------------------------------------------------------------------------
__global__ __launch_bounds__(256) void k_qkt(const float* __restrict__ W,
                                             const float* __restrict__ X,
                                             _Float16* __restrict__ QT) {
  __shared__ float xs[128 * 64];
  __shared__ float wsh[128 * 33];
  const int tid = threadIdx.x;
  const int n0 = blockIdx.x * 64, b = blockIdx.z;
  const float* Xb = X + (size_t)(b * C) * N + n0;
#pragma unroll
  for (int i = 0; i < 8; i++) {
    int idx = tid + i * 256;
    int c = idx >> 4, q = idx & 15;
    *(float4*)&xs[c * 64 + q * 4] = *(const float4*)&Xb[(size_t)c * N + q * 4];
  }
#pragma unroll
  for (int i = 0; i < 16; i++) {
    int idx = tid + i * 256;
    int c = idx & 127, o = idx >> 7;   // o in [0,32)
    wsh[c * 33 + o] = W[o * C + c];
  }
  __syncthreads();
  const int to = tid >> 4, tn = tid & 15;
  float acc[2][4];
#pragma unroll
  for (int i = 0; i < 2; i++)
#pragma unroll
    for (int j = 0; j < 4; j++) acc[i][j] = 0.f;
#pragma unroll 4
  for (int c = 0; c < 128; c++) {
    const float4 x4 = *(const float4*)&xs[c * 64 + tn * 4];
    const float w0 = wsh[c * 33 + to * 2], w1 = wsh[c * 33 + to * 2 + 1];
    acc[0][0] += w0 * x4.x; acc[0][1] += w0 * x4.y; acc[0][2] += w0 * x4.z; acc[0][3] += w0 * x4.w;
    acc[1][0] += w1 * x4.x; acc[1][1] += w1 * x4.y; acc[1][2] += w1 * x4.z; acc[1][3] += w1 * x4.w;
  }
  _Float16* Qb = QT + ((size_t)b * N + n0) * 32;
#pragma unroll
  for (int j = 0; j < 4; j++) {
    f16x2 h = {(_Float16)acc[0][j], (_Float16)acc[1][j]};
    *(f16x2*)&Qb[(tn * 4 + j) * 32 + to * 2] = h;
  }
}

// ---------------------------------------------------------------------------
// Energy Gram matrix via MFMA f16: E[bl,n,m] = sum_o QT[n][o]*QT[m][o].
// grid (N/64 m, N/64 n, bg), block 256.
// ---------------------------------------------------------------------------
__global__ __launch_bounds__(256) void k_energy(const _Float16* __restrict__ QT,
                                                _Float16* __restrict__ E, int b0) {
  __shared__ _Float16 Qn[64 * 40];
  __shared__ _Float16 Qm[64 * 40];
  __shared__ _Float16 Ts[64 * 72];
  const int tid = threadIdx.x;
  const int m0 = blockIdx.x * 64, n0 = blockIdx.y * 64, bl = blockIdx.z, b = b0 + bl;
  const _Float16* Qb = QT + (size_t)b * N * 32;
#pragma unroll
  for (int i = 0; i < 2; i++) {
    int idx = tid + i * 256;            // 0..511
    int r = (idx >> 2) & 63, ch = idx & 3;
    int base = (idx >> 8) ? m0 : n0;
    _Float16* dst = (idx >> 8) ? Qm : Qn;
    *(f16x8*)&dst[r * 40 + ch * 8] = *(const f16x8*)&Qb[(size_t)(base + r) * 32 + ch * 8];
  }
  __syncthreads();
  const int w = tid >> 6, lane = tid & 63, quad = lane >> 4, lr = lane & 15;
  f32x4 acc[4];
#pragma unroll
  for (int mi = 0; mi < 4; mi++) acc[mi] = (f32x4){0.f, 0.f, 0.f, 0.f};
  const f16x8 aF = *(const f16x8*)&Qn[(w * 16 + lr) * 40 + quad * 8];
#pragma unroll
  for (int mi = 0; mi < 4; mi++) {
    const f16x8 bF = *(const f16x8*)&Qm[(mi * 16 + lr) * 40 + quad * 8];
    acc[mi] = __builtin_amdgcn_mfma_f32_16x16x32_f16(aF, bF, acc[mi], 0, 0, 0);
  }
#pragma unroll
  for (int mi = 0; mi < 4; mi++)
#pragma unroll
    for (int r = 0; r < 4; r++)
      Ts[(w * 16 + quad * 4 + r) * 72 + mi * 16 + lr] = (_Float16)acc[mi][r];
  __syncthreads();
#pragma unroll
  for (int i = 0; i < 2; i++) {
    int idx = tid + i * 256;
    int r = idx >> 3, ch = idx & 7;
    *(f16x8*)&E[((size_t)bl * N + n0 + r) * N + m0 + ch * 8] = *(const f16x8*)&Ts[r * 72 + ch * 8];
  }
}

// ---------------------------------------------------------------------------
// Row softmax stats for ALL rows. Valid: rm=max, ri=1/sum (ri >= 1/4096 > 0).
// Invalid row: rm=1e30, ri=0  (consumer decodes ri==0 -> P = 1/4096).
// grid (N, bg), 256 thr.
// ---------------------------------------------------------------------------
__global__ __launch_bounds__(256) void k_rs(const _Float16* __restrict__ E,
                                            const int* __restrict__ mask,
                                            float* __restrict__ rowmax,
                                            float* __restrict__ rowsi, int b0) {
  const int r = blockIdx.x, bl = blockIdx.y, b = b0 + bl, tid = threadIdx.x;
  if (mask[b * N + r] == 0) {
    if (tid == 0) { rowmax[b * N + r] = 1e30f; rowsi[b * N + r] = 0.0f; }
    return;
  }
  const _Float16* Er = E + ((size_t)bl * N + r) * N;
  const int* Mb = mask + b * N;
  float ev[16]; int va[16];
  float mx = -3.0e38f;
#pragma unroll
  for (int v = 0; v < 2; v++) {
    const int nb = (tid + v * 256) * 8;
    const f16x8 e8 = *(const f16x8*)&Er[nb];
    const int4 ma = *(const int4*)&Mb[nb];
    const int4 mb2 = *(const int4*)&Mb[nb + 4];
    const int ml[8] = {ma.x, ma.y, ma.z, ma.w, mb2.x, mb2.y, mb2.z, mb2.w};
#pragma unroll
    for (int j = 0; j < 8; j++) {
      const float e = (float)e8[j];
      ev[v * 8 + j] = e; va[v * 8 + j] = ml[j];
      if (ml[j] && e > mx) mx = e;
    }
  }
#pragma unroll
  for (int o = 32; o > 0; o >>= 1) mx = fmaxf(mx, __shfl_down(mx, o, 64));
  __shared__ float red[4], red2[4];
  if ((tid & 63) == 0) red[tid >> 6] = mx;
  __syncthreads();
  mx = fmaxf(fmaxf(red[0], red[1]), fmaxf(red[2], red[3]));
  float s = 0.f;
#pragma unroll
  for (int i = 0; i < 16; i++)
    if (va[i]) s += __expf(ev[i] - mx);
#pragma unroll
  for (int o = 32; o > 0; o >>= 1) s += __shfl_down(s, o, 64);
  if ((tid & 63) == 0) red2[tid >> 6] = s;
  __syncthreads();
  if (tid == 0) {
    s = red2[0] + red2[1] + red2[2] + red2[3];
    rowmax[b * N + r] = mx;
    rowsi[b * N + r] = 1.0f / s;
  }
}

// ---------------------------------------------------------------------------
// Fused P-transform + x_r GEMM. R3: 512-thr blocks + C-split for occupancy
// (was 256 blocks = 4 waves/CU, latency-bound at 11% occupancy).
// grid (N/64 m, 2 c-half, bg), block 512 = 8 waves, 2 blocks/CU -> 16 waves/CU.
// Waves 0-3 produce PT tile (exp transform of E + colsum), waves 4-7 stage XV
// half-tile; all 8 waves run MFMA. PT[m][n] = vm*exp(E[m][n]-rm[n])*ri[n]
// (ri==0 -> fully-masked row n -> 1/4096). Td = H - acc/(1e-9+colsum).
// ---------------------------------------------------------------------------
__global__ __launch_bounds__(512) void k_xr(const _Float16* __restrict__ XV,
                                            const _Float16* __restrict__ E,
                                            const float* __restrict__ H,
                                            const int* __restrict__ mask,
                                            const float* __restrict__ rowmax,
                                            const float* __restrict__ rowsi,
                                            float* __restrict__ Td, int b0) {
  __shared__ _Float16 As[64 * 40];
  __shared__ _Float16 Bs[64 * 40];
  __shared__ float colS[64];
  const int tid = threadIdx.x;
  const int m0 = blockIdx.x * 64, ch0 = blockIdx.y * 64, bl = blockIdx.z, b = b0 + bl;
  const _Float16* Ab = XV + (size_t)(b * C + ch0) * N;
  const _Float16* Eb = E + ((size_t)bl * N + m0) * N;
  const int w = tid >> 6, lane = tid & 63, quad = lane >> 4, lr = lane & 15;
  const int wc = w & 3, wm = w >> 2;          // wave owns c-rows wc*16, m-rows wm*32
  const int mB = tid >> 2, chB = tid & 3;     // B-producer assignment (tid<256)
  const float vm = (tid < 256 && mask[b * N + m0 + mB] != 0) ? 1.0f : 0.0f;
  const int idxA = tid - 256, cA = idxA >> 2, chA = idxA & 3;  // A-stager (tid>=256)
  const float* rmB = rowmax + b * N;
  const float* riB = rowsi + b * N;
  float cs = 0.f;
  f32x4 acc[2];
  acc[0] = (f32x4){0.f, 0.f, 0.f, 0.f};
  acc[1] = (f32x4){0.f, 0.f, 0.f, 0.f};
  for (int k0 = 0; k0 < N; k0 += 32) {
    if (tid < 256) {
      const int nb = k0 + chB * 8;
      const f16x8 e8 = *(const f16x8*)&Eb[(size_t)mB * N + nb];
      const float4 rm0 = *(const float4*)&rmB[nb], rm1 = *(const float4*)&rmB[nb + 4];
      const float4 ri0 = *(const float4*)&riB[nb], ri1 = *(const float4*)&riB[nb + 4];
      const float rmv[8] = {rm0.x, rm0.y, rm0.z, rm0.w, rm1.x, rm1.y, rm1.z, rm1.w};
      const float riv[8] = {ri0.x, ri0.y, ri0.z, ri0.w, ri1.x, ri1.y, ri1.z, ri1.w};
      f16x8 p8;
#pragma unroll
      for (int j = 0; j < 8; j++) {
        const float base = vm * __expf((float)e8[j] - rmv[j]) * riv[j];
        const float p = (riv[j] == 0.0f) ? 0.000244140625f : base;  // 1/4096
        cs += p;
        p8[j] = (_Float16)p;
      }
      *(f16x8*)&Bs[mB * 40 + chB * 8] = p8;
    } else {
      *(f16x8*)&As[cA * 40 + chA * 8] = *(const f16x8*)&Ab[(size_t)cA * N + k0 + chA * 8];
    }
    __syncthreads();
    const f16x8 af = *(const f16x8*)&As[(wc * 16 + lr) * 40 + quad * 8];
    f16x8 bf[2];
#pragma unroll
    for (int mi = 0; mi < 2; mi++)
      bf[mi] = *(const f16x8*)&Bs[(wm * 32 + mi * 16 + lr) * 40 + quad * 8];
#pragma unroll
    for (int mi = 0; mi < 2; mi++)
      acc[mi] = __builtin_amdgcn_mfma_f32_16x16x32_f16(af, bf[mi], acc[mi], 0, 0, 0);
    __syncthreads();
  }
  // colsum: threads 4m..4m+3 (same wave, waves 0-3) hold partials for row m
  if (tid < 256) {
    cs += __shfl_down(cs, 1, 64);
    cs += __shfl_down(cs, 2, 64);
    if ((tid & 3) == 0) colS[mB] = cs;
  }
  __syncthreads();
#pragma unroll
  for (int mi = 0; mi < 2; mi++) {
    const int ml = wm * 32 + mi * 16 + lr;
    const int m = m0 + ml;
    const float rdiv = 1.0f / (1e-9f + colS[ml]);
    const int cb = ch0 + wc * 16 + quad * 4;
#pragma unroll
    for (int r = 0; r < 4; r++) {
      const size_t gi = (size_t)(b * C + cb + r) * N + m;
      Td[gi] = H[gi] - acc[mi][r] * rdiv;
    }
  }
}

// ---------------------------------------------------------------------------
// BatchNorm stats over (B,N) per channel -> scale/shift. grid (C), 256 thr.
// ---------------------------------------------------------------------------
__global__ __launch_bounds__(256) void k_bnstats(const float* __restrict__ X,
                                                 const float* __restrict__ gamma,
                                                 const float* __restrict__ beta,
                                                 float* __restrict__ ss) {
  const int c = blockIdx.x, tid = threadIdx.x;
  float s = 0.f, s2 = 0.f;
  const float* base = X + (size_t)c * N;
  for (int i = tid; i < B * N; i += 256) {
    const float v = base[(size_t)(i >> 12) * (C * N) + (i & (N - 1))];
    s += v; s2 += v * v;
  }
#pragma unroll
  for (int o = 32; o > 0; o >>= 1) { s += __shfl_down(s, o, 64); s2 += __shfl_down(s2, o, 64); }
  __shared__ float r1[4], r2[4];
  if ((tid & 63) == 0) { r1[tid >> 6] = s; r2[tid >> 6] = s2; }
  __syncthreads();
  if (tid == 0) {
    s = r1[0] + r1[1] + r1[2] + r1[3];
    s2 = r2[0] + r2[1] + r2[2] + r2[3];
    const float inv = 1.0f / (B * N);
    const float mean = s * inv;
    const float var = s2 * inv - mean * mean;   // biased, like torch BN
    const float sc = gamma[c] * rsqrtf(var + 1e-5f);
    ss[2 * c] = sc;
    ss[2 * c + 1] = beta[c] - mean * sc;
  }
}

// ---------------------------------------------------------------------------
// Apply BN+ReLU (+residual, +write output slice). grid 2048, 256 thr, float4.
// ---------------------------------------------------------------------------
template<bool RES>
__global__ __launch_bounds__(256) void k_apply(const float* __restrict__ T2,
                                               const float* __restrict__ ss,
                                               float* __restrict__ H,
                                               float* __restrict__ Out) {
  const int i = blockIdx.x * 256 + threadIdx.x;   // float4 index
  const int f = i * 4;
  const int c = (f >> 12) & 127;
  const float sc = ss[2 * c], sh = ss[2 * c + 1];
  const float4 t = *(const float4*)&T2[f];
  float4 r;
  r.x = fmaxf(t.x * sc + sh, 0.f);
  r.y = fmaxf(t.y * sc + sh, 0.f);
  r.z = fmaxf(t.z * sc + sh, 0.f);
  r.w = fmaxf(t.w * sc + sh, 0.f);
  if (RES) {
    const float4 h = *(const float4*)&H[f];
    r.x += h.x; r.y += h.y; r.z += h.z; r.w += h.w;
    *(float4*)&H[f] = r;
    const int b = f >> 19;                // f / (C*N)
    const int rem = f & (C * N - 1);      // c*N + n
    *(float4*)&Out[(size_t)b * (4 * C * N) + rem] = r;
  } else {
    *(float4*)&H[f] = r;
  }
}

// ---------------------------------------------------------------------------
extern "C" void kernel_launch(void* const* d_in, const int* in_sizes, int n_in,
                              void* d_out, int out_size, void* d_ws, size_t ws_size,
                              hipStream_t stream) {
  const float* x    = (const float*)d_in[0];
  const int*   mask = (const int*)  d_in[1];
  const float* w1   = (const float*)d_in[2];
  const float* g1   = (const float*)d_in[3];
  const float* b1   = (const float*)d_in[4];
  const float* w2   = (const float*)d_in[5];
  const float* g2   = (const float*)d_in[6];
  const float* b2   = (const float*)d_in[7];
  const float* wqk  = (const float*)d_in[8];
  const float* wv   = (const float*)d_in[9];
  const float* bv   = (const float*)d_in[10];
  const float* wt   = (const float*)d_in[11];
  const float* bt   = (const float*)d_in[12];
  const float* sg   = (const float*)d_in[13];
  const float* sb   = (const float*)d_in[14];
  float* out = (float*)d_out;

  char* p = (char*)d_ws;
  auto alloc = [&](size_t bytes) { char* r = p; p += (bytes + 255) & ~(size_t)255; return r; };
  float*    H      = (float*)   alloc((size_t)B * C * N * 4);
  float*    T2     = (float*)   alloc((size_t)B * C * N * 4);
  float*    Td     = (float*)   alloc((size_t)B * C * N * 4);
  _Float16* XQKT   = (_Float16*)alloc((size_t)B * N * 32 * 2);
  _Float16* XV     = (_Float16*)alloc((size_t)B * C * N * 2);
  float*    rowmax = (float*)   alloc((size_t)B * N * 4);
  float*    rowsi  = (float*)   alloc((size_t)B * N * 4);
  float*    ss     = (float*)   alloc((size_t)C * 2 * 4);
  const size_t fixedEnd = (size_t)(p - (char*)d_ws);
  const size_t e1 = (size_t)N * (size_t)N * 2;
  const int bg = (ws_size >= fixedEnd + 4 * e1) ? 4 : 1;   // batches per E pass
  _Float16* E = (_Float16*)p;

  // ---- stem: two conv1d(+BN+ReLU) ----
  k_gw<false, false><<<dim3(64, 2, B), 256, 0, stream>>>(w1, x, nullptr, T2);
  k_bnstats<<<C, 256, 0, stream>>>(T2, g1, b1, ss);
  k_apply<false><<<2048, 256, 0, stream>>>(T2, ss, H, nullptr);
  k_gw<false, false><<<dim3(64, 2, B), 256, 0, stream>>>(w2, H, nullptr, T2);
  k_bnstats<<<C, 256, 0, stream>>>(T2, g2, b2, ss);
  k_apply<false><<<2048, 256, 0, stream>>>(T2, ss, H, nullptr);

  // ---- 4 chained offset-attention layers ----
  for (int L = 0; L < 4; L++) {
    k_qkt<<<dim3(64, 1, B), 256, 0, stream>>>(wqk + (size_t)L * 32 * C, H, XQKT);
    k_gw<true, true><<<dim3(64, 2, B), 256, 0, stream>>>(wv + (size_t)L * C * C, H, bv + L * C, XV);
    for (int b0 = 0; b0 < B; b0 += bg) {
      k_energy<<<dim3(64, 64, bg), 256, 0, stream>>>(XQKT, E, b0);
      k_rs<<<dim3(N, bg), 256, 0, stream>>>(E, mask, rowmax, rowsi, b0);
      k_xr<<<dim3(64, 2, bg), 512, 0, stream>>>(XV, E, H, mask, rowmax, rowsi, Td, b0);
    }
    k_gw<true, false><<<dim3(64, 2, B), 256, 0, stream>>>(wt + (size_t)L * C * C, Td, bt + L * C, T2);
    k_bnstats<<<C, 256, 0, stream>>>(T2, sg + L * C, sb + L * C, ss);
    k_apply<true><<<2048, 256, 0, stream>>>(T2, ss, H, out + (size_t)L * C * N);
  }
}

// Round 5
// 724.948 us; speedup vs baseline: 1.4742x; 1.2458x over previous
//
#include <hip/hip_runtime.h>
#include <hip/hip_fp16.h>

constexpr int C = 128;
constexpr int N = 4096;
constexpr int B = 4;

typedef _Float16 f16x8 __attribute__((ext_vector_type(8)));
typedef _Float16 f16x4 __attribute__((ext_vector_type(4)));
typedef _Float16 f16x2 __attribute__((ext_vector_type(2)));
typedef float    f32x4 __attribute__((ext_vector_type(4)));

// ---------------------------------------------------------------------------
// Small GEMM: Y[b,o,n] = sum_c W[o,c] * X[b,c,n] (+bias[o]); O=128 fixed.
// grid (N/64, 2, B), block 256. fp32 compute; optional fp16 output.
// ---------------------------------------------------------------------------
template<bool BIAS, bool HALFOUT>
__global__ __launch_bounds__(256) void k_gw(const float* __restrict__ W,
                                            const float* __restrict__ X,
                                            const float* __restrict__ bias,
                                            void* __restrict__ Yv) {
  __shared__ float xs[128 * 64];
  __shared__ float wsh[128 * 65];
  const int tid = threadIdx.x;
  const int n0 = blockIdx.x * 64, o0 = blockIdx.y * 64, b = blockIdx.z;
  const float* Xb = X + (size_t)(b * C) * N + n0;
#pragma unroll
  for (int i = 0; i < 8; i++) {
    int idx = tid + i * 256;
    int c = idx >> 4, q = idx & 15;
    *(float4*)&xs[c * 64 + q * 4] = *(const float4*)&Xb[(size_t)c * N + q * 4];
  }
#pragma unroll
  for (int i = 0; i < 32; i++) {
    int idx = tid + i * 256;
    int c = idx & 127, o = idx >> 7;
    wsh[c * 65 + o] = W[(o0 + o) * C + c];
  }
  __syncthreads();
  const int to = tid >> 4, tn = tid & 15;
  float acc[4][4];
#pragma unroll
  for (int i = 0; i < 4; i++)
#pragma unroll
    for (int j = 0; j < 4; j++) acc[i][j] = 0.f;
#pragma unroll 4
  for (int c = 0; c < 128; c++) {
    const float4 x4 = *(const float4*)&xs[c * 64 + tn * 4];
    const float* wp = &wsh[c * 65 + to * 4];
    const float w0 = wp[0], w1 = wp[1], w2 = wp[2], w3 = wp[3];
    acc[0][0] += w0 * x4.x; acc[0][1] += w0 * x4.y; acc[0][2] += w0 * x4.z; acc[0][3] += w0 * x4.w;
    acc[1][0] += w1 * x4.x; acc[1][1] += w1 * x4.y; acc[1][2] += w1 * x4.z; acc[1][3] += w1 * x4.w;
    acc[2][0] += w2 * x4.x; acc[2][1] += w2 * x4.y; acc[2][2] += w2 * x4.z; acc[2][3] += w2 * x4.w;
    acc[3][0] += w3 * x4.x; acc[3][1] += w3 * x4.y; acc[3][2] += w3 * x4.z; acc[3][3] += w3 * x4.w;
  }
  const int ob = o0 + to * 4, nb = n0 + tn * 4;
#pragma unroll
  for (int i = 0; i < 4; i++) {
    const float bv_ = BIAS ? bias[ob + i] : 0.f;
    const float r0 = acc[i][0] + bv_, r1 = acc[i][1] + bv_, r2 = acc[i][2] + bv_, r3 = acc[i][3] + bv_;
    const size_t gi = (size_t)(b * C + ob + i) * N + nb;
    if (HALFOUT) {
      f16x4 h = {(_Float16)r0, (_Float16)r1, (_Float16)r2, (_Float16)r3};
      *(f16x4*)((_Float16*)Yv + gi) = h;
    } else {
      float4 r; r.x = r0; r.y = r1; r.z = r2; r.w = r3;
      *(float4*)((float*)Yv + gi) = r;
    }
  }
}

// ---------------------------------------------------------------------------
// QK projection with TRANSPOSED fp16 output: QT[b][n][o] (o<32).
// grid (N/64, 1, B), block 256.
// ---------------------------------------------------------------------------
__global__ __launch_bounds__(256) void k_qkt(const float* __restrict__ W,
                                             const float* __restrict__ X,
                                             _Float16* __restrict__ QT) {
  __shared__ float xs[128 * 64];
  __shared__ float wsh[128 * 33];
  const int tid = threadIdx.x;
  const int n0 = blockIdx.x * 64, b = blockIdx.z;
  const float* Xb = X + (size_t)(b * C) * N + n0;
#pragma unroll
  for (int i = 0; i < 8; i++) {
    int idx = tid + i * 256;
    int c = idx >> 4, q = idx & 15;
    *(float4*)&xs[c * 64 + q * 4] = *(const float4*)&Xb[(size_t)c * N + q * 4];
  }
#pragma unroll
  for (int i = 0; i < 16; i++) {
    int idx = tid + i * 256;
    int c = idx & 127, o = idx >> 7;   // o in [0,32)
    wsh[c * 33 + o] = W[o * C + c];
  }
  __syncthreads();
  const int to = tid >> 4, tn = tid & 15;
  float acc[2][4];
#pragma unroll
  for (int i = 0; i < 2; i++)
#pragma unroll
    for (int j = 0; j < 4; j++) acc[i][j] = 0.f;
#pragma unroll 4
  for (int c = 0; c < 128; c++) {
    const float4 x4 = *(const float4*)&xs[c * 64 + tn * 4];
    const float w0 = wsh[c * 33 + to * 2], w1 = wsh[c * 33 + to * 2 + 1];
    acc[0][0] += w0 * x4.x; acc[0][1] += w0 * x4.y; acc[0][2] += w0 * x4.z; acc[0][3] += w0 * x4.w;
    acc[1][0] += w1 * x4.x; acc[1][1] += w1 * x4.y; acc[1][2] += w1 * x4.z; acc[1][3] += w1 * x4.w;
  }
  _Float16* Qb = QT + ((size_t)b * N + n0) * 32;
#pragma unroll
  for (int j = 0; j < 4; j++) {
    f16x2 h = {(_Float16)acc[0][j], (_Float16)acc[1][j]};
    *(f16x2*)&Qb[(tn * 4 + j) * 32 + to * 2] = h;
  }
}

// ---------------------------------------------------------------------------
// R4: flash-style row-stats WITHOUT materializing E.
// Per block: 64 n-rows; sweep all m recomputing E=QT[n]·QT[m] via MFMA.
// Pass 1: masked max (mask as additive -1e30 bias); pass 2: exp-sum.
// Valid row: rm=max, ri=1/sum. Invalid row: rm=1e30, ri=0 (consumer: P=1/4096).
// grid (N/64, B), block 512 (8 waves: wave w -> n-sub w&3, m-half w>>2).
// ---------------------------------------------------------------------------
__global__ __launch_bounds__(512) void k_sm(const _Float16* __restrict__ QT,
                                            const int* __restrict__ mask,
                                            float* __restrict__ rowmax,
                                            float* __restrict__ rowsi) {
  __shared__ float mb[N];          // 0 (valid m) or -1e30 (invalid m)
  __shared__ float red[2][64];
  __shared__ float rmS[64];
  const int tid = threadIdx.x;
  const int n0 = blockIdx.x * 64, b = blockIdx.y;
  const _Float16* Qb = QT + (size_t)b * N * 32;
  const int* Mb = mask + b * N;
#pragma unroll
  for (int i = 0; i < 8; i++) {
    const int v = tid + i * 512;
    mb[v] = (Mb[v] != 0) ? 0.0f : -1e30f;
  }
  const int w = tid >> 6, lane = tid & 63, quad = lane >> 4, lr = lane & 15;
  const int nw = (w & 3) * 16, mh = (w >> 2) * 64;
  const f16x8 aF = *(const f16x8*)&Qb[(size_t)(n0 + nw + lr) * 32 + quad * 8];
  __syncthreads();
  // ---- pass 1: masked max ----
  float mx[4] = {-3e38f, -3e38f, -3e38f, -3e38f};
  for (int ms = 0; ms < N; ms += 128) {
#pragma unroll
    for (int t = 0; t < 4; t++) {
      const int mrow = ms + mh + t * 16 + lr;
      const f16x8 bF = *(const f16x8*)&Qb[(size_t)mrow * 32 + quad * 8];
      f32x4 d = (f32x4){0.f, 0.f, 0.f, 0.f};
      d = __builtin_amdgcn_mfma_f32_16x16x32_f16(aF, bF, d, 0, 0, 0);
      const float bias = mb[mrow];
#pragma unroll
      for (int r = 0; r < 4; r++) mx[r] = fmaxf(mx[r], d[r] + bias);
    }
  }
#pragma unroll
  for (int r = 0; r < 4; r++) {
    float v = mx[r];
    v = fmaxf(v, __shfl_xor(v, 1, 64));
    v = fmaxf(v, __shfl_xor(v, 2, 64));
    v = fmaxf(v, __shfl_xor(v, 4, 64));
    v = fmaxf(v, __shfl_xor(v, 8, 64));
    mx[r] = v;
  }
  if (lr == 0)
#pragma unroll
    for (int r = 0; r < 4; r++) red[w >> 2][nw + quad * 4 + r] = mx[r];
  __syncthreads();
  if (tid < 64) rmS[tid] = fmaxf(red[0][tid], red[1][tid]);
  __syncthreads();
  // ---- pass 2: exp-sum ----
  float rmr[4];
#pragma unroll
  for (int r = 0; r < 4; r++) rmr[r] = rmS[nw + quad * 4 + r];
  float s[4] = {0.f, 0.f, 0.f, 0.f};
  for (int ms = 0; ms < N; ms += 128) {
#pragma unroll
    for (int t = 0; t < 4; t++) {
      const int mrow = ms + mh + t * 16 + lr;
      const f16x8 bF = *(const f16x8*)&Qb[(size_t)mrow * 32 + quad * 8];
      f32x4 d = (f32x4){0.f, 0.f, 0.f, 0.f};
      d = __builtin_amdgcn_mfma_f32_16x16x32_f16(aF, bF, d, 0, 0, 0);
      const float bias = mb[mrow];
#pragma unroll
      for (int r = 0; r < 4; r++) s[r] += __expf(d[r] + bias - rmr[r]);
    }
  }
#pragma unroll
  for (int r = 0; r < 4; r++) {
    float v = s[r];
    v += __shfl_xor(v, 1, 64);
    v += __shfl_xor(v, 2, 64);
    v += __shfl_xor(v, 4, 64);
    v += __shfl_xor(v, 8, 64);
    s[r] = v;
  }
  __syncthreads();   // red reused
  if (lr == 0)
#pragma unroll
    for (int r = 0; r < 4; r++) red[w >> 2][nw + quad * 4 + r] = s[r];
  __syncthreads();
  if (tid < 64) {
    const int row = n0 + tid;
    const float tot = red[0][tid] + red[1][tid];
    const bool valid = (Mb[row] != 0);
    rowmax[b * N + row] = valid ? rmS[tid] : 1e30f;
    rowsi[b * N + row] = valid ? (1.0f / tot) : 0.0f;
  }
}

// ---------------------------------------------------------------------------
// R4: fused Gram->exp->PV (flash-style; E never materialized).
// Per (32 m-cols, batch) block, per 64-n step:
//   Gram MFMA (1/wave) -> E regs; exp transform -> Ps LDS (PV B-layout);
//   colsum in-reg; stage XV tile; 4 PV MFMA/wave.
// Td[b,c,m] = H - (sum_n XV[c,n]*P[m,n]) / (1e-9 + colsum[m]).
// grid (N/32, B), block 512 (8 waves: Gram msub=w&1 nsub=w>>1; PV c-rows w*16).
// ---------------------------------------------------------------------------
__global__ __launch_bounds__(512, 4) void k_pv(const _Float16* __restrict__ QT,
                                               const _Float16* __restrict__ XV,
                                               const float* __restrict__ H,
                                               const int* __restrict__ mask,
                                               const float* __restrict__ rowmax,
                                               const float* __restrict__ rowsi,
                                               float* __restrict__ Td) {
  __shared__ _Float16 XVs[128 * 72];
  __shared__ _Float16 Ps[32 * 72];
  __shared__ float colPart[4][32];
  __shared__ float colS[32];
  const int tid = threadIdx.x;
  const int m0 = blockIdx.x * 32, b = blockIdx.y;
  const _Float16* Qb = QT + (size_t)b * N * 32;
  const _Float16* XVb = XV + (size_t)(b * C) * N;
  const float* rmB = rowmax + b * N;
  const float* riB = rowsi + b * N;
  const int w = tid >> 6, lane = tid & 63, quad = lane >> 4, lr = lane & 15;
  const int msub = w & 1, nsub = w >> 1;
  const f16x8 aG = *(const f16x8*)&Qb[(size_t)(m0 + msub * 16 + lr) * 32 + quad * 8];
  float vmb[4];   // additive mask bias for this lane's 4 m-rows
#pragma unroll
  for (int r = 0; r < 4; r++)
    vmb[r] = (mask[b * N + m0 + msub * 16 + quad * 4 + r] != 0) ? 0.0f : -1e30f;
  const int sc0 = tid >> 3, sh0 = tid & 7;          // XV staging (2 vec/thread)
  const int sc1 = (tid + 512) >> 3, sh1 = (tid + 512) & 7;
  f32x4 acc[2];
  acc[0] = (f32x4){0.f, 0.f, 0.f, 0.f};
  acc[1] = (f32x4){0.f, 0.f, 0.f, 0.f};
  float cs[4] = {0.f, 0.f, 0.f, 0.f};
  for (int k0 = 0; k0 < N; k0 += 64) {
    // Gram for n-range [k0, k0+64): no LDS dependence
    const int nn = k0 + nsub * 16 + lr;
    const f16x8 bG = *(const f16x8*)&Qb[(size_t)nn * 32 + quad * 8];
    const float rmv = rmB[nn], riv = riB[nn];
    f32x4 e = (f32x4){0.f, 0.f, 0.f, 0.f};
    e = __builtin_amdgcn_mfma_f32_16x16x32_f16(aG, bG, e, 0, 0, 0);
    __syncthreads();              // prev step's PV reads complete
    *(f16x8*)&XVs[sc0 * 72 + sh0 * 8] = *(const f16x8*)&XVb[(size_t)sc0 * N + k0 + sh0 * 8];
    *(f16x8*)&XVs[sc1 * 72 + sh1 * 8] = *(const f16x8*)&XVb[(size_t)sc1 * N + k0 + sh1 * 8];
#pragma unroll
    for (int r = 0; r < 4; r++) {
      float p = __expf(e[r] - rmv + vmb[r]) * riv;
      p = (riv == 0.0f) ? 0.000244140625f : p;      // fully-masked row n
      cs[r] += p;
      Ps[(msub * 16 + quad * 4 + r) * 72 + nsub * 16 + lr] = (_Float16)p;
    }
    __syncthreads();              // Ps + XVs ready
    const int c0 = w * 16;
    const f16x8 a0 = *(const f16x8*)&XVs[(c0 + lr) * 72 + quad * 8];
    const f16x8 a1 = *(const f16x8*)&XVs[(c0 + lr) * 72 + 32 + quad * 8];
    const f16x8 b00 = *(const f16x8*)&Ps[lr * 72 + quad * 8];
    const f16x8 b01 = *(const f16x8*)&Ps[lr * 72 + 32 + quad * 8];
    const f16x8 b10 = *(const f16x8*)&Ps[(16 + lr) * 72 + quad * 8];
    const f16x8 b11 = *(const f16x8*)&Ps[(16 + lr) * 72 + 32 + quad * 8];
    acc[0] = __builtin_amdgcn_mfma_f32_16x16x32_f16(a0, b00, acc[0], 0, 0, 0);
    acc[0] = __builtin_amdgcn_mfma_f32_16x16x32_f16(a1, b01, acc[0], 0, 0, 0);
    acc[1] = __builtin_amdgcn_mfma_f32_16x16x32_f16(a0, b10, acc[1], 0, 0, 0);
    acc[1] = __builtin_amdgcn_mfma_f32_16x16x32_f16(a1, b11, acc[1], 0, 0, 0);
  }
  // colsum: reduce each cs[r] across the 16 lanes of the quad, then 4 n-waves
#pragma unroll
  for (int r = 0; r < 4; r++) {
    float v = cs[r];
    v += __shfl_xor(v, 1, 64);
    v += __shfl_xor(v, 2, 64);
    v += __shfl_xor(v, 4, 64);
    v += __shfl_xor(v, 8, 64);
    cs[r] = v;
  }
  if (lr == 0)
#pragma unroll
    for (int r = 0; r < 4; r++) colPart[nsub][msub * 16 + quad * 4 + r] = cs[r];
  __syncthreads();
  if (tid < 32)
    colS[tid] = colPart[0][tid] + colPart[1][tid] + colPart[2][tid] + colPart[3][tid];
  __syncthreads();
  const float rdiv0 = 1.0f / (1e-9f + colS[lr]);
  const float rdiv1 = 1.0f / (1e-9f + colS[16 + lr]);
  const int cg = b * C + w * 16 + quad * 4;
#pragma unroll
  for (int r = 0; r < 4; r++) {
    const size_t gi0 = (size_t)(cg + r) * N + m0 + lr;
    Td[gi0] = H[gi0] - acc[0][r] * rdiv0;
    const size_t gi1 = (size_t)(cg + r) * N + m0 + 16 + lr;
    Td[gi1] = H[gi1] - acc[1][r] * rdiv1;
  }
}

// ---------------------------------------------------------------------------
// BatchNorm stats over (B,N) per channel -> scale/shift. grid (C), 256 thr.
// ---------------------------------------------------------------------------
__global__ __launch_bounds__(256) void k_bnstats(const float* __restrict__ X,
                                                 const float* __restrict__ gamma,
                                                 const float* __restrict__ beta,
                                                 float* __restrict__ ss) {
  const int c = blockIdx.x, tid = threadIdx.x;
  float s = 0.f, s2 = 0.f;
  const float* base = X + (size_t)c * N;
  for (int i = tid; i < B * N; i += 256) {
    const float v = base[(size_t)(i >> 12) * (C * N) + (i & (N - 1))];
    s += v; s2 += v * v;
  }
#pragma unroll
  for (int o = 32; o > 0; o >>= 1) { s += __shfl_down(s, o, 64); s2 += __shfl_down(s2, o, 64); }
  __shared__ float r1[4], r2[4];
  if ((tid & 63) == 0) { r1[tid >> 6] = s; r2[tid >> 6] = s2; }
  __syncthreads();
  if (tid == 0) {
    s = r1[0] + r1[1] + r1[2] + r1[3];
    s2 = r2[0] + r2[1] + r2[2] + r2[3];
    const float inv = 1.0f / (B * N);
    const float mean = s * inv;
    const float var = s2 * inv - mean * mean;   // biased, like torch BN
    const float sc = gamma[c] * rsqrtf(var + 1e-5f);
    ss[2 * c] = sc;
    ss[2 * c + 1] = beta[c] - mean * sc;
  }
}

// ---------------------------------------------------------------------------
// Apply BN+ReLU (+residual, +write output slice). grid 2048, 256 thr, float4.
// ---------------------------------------------------------------------------
template<bool RES>
__global__ __launch_bounds__(256) void k_apply(const float* __restrict__ T2,
                                               const float* __restrict__ ss,
                                               float* __restrict__ H,
                                               float* __restrict__ Out) {
  const int i = blockIdx.x * 256 + threadIdx.x;   // float4 index
  const int f = i * 4;
  const int c = (f >> 12) & 127;
  const float sc = ss[2 * c], sh = ss[2 * c + 1];
  const float4 t = *(const float4*)&T2[f];
  float4 r;
  r.x = fmaxf(t.x * sc + sh, 0.f);
  r.y = fmaxf(t.y * sc + sh, 0.f);
  r.z = fmaxf(t.z * sc + sh, 0.f);
  r.w = fmaxf(t.w * sc + sh, 0.f);
  if (RES) {
    const float4 h = *(const float4*)&H[f];
    r.x += h.x; r.y += h.y; r.z += h.z; r.w += h.w;
    *(float4*)&H[f] = r;
    const int b = f >> 19;                // f / (C*N)
    const int rem = f & (C * N - 1);      // c*N + n
    *(float4*)&Out[(size_t)b * (4 * C * N) + rem] = r;
  } else {
    *(float4*)&H[f] = r;
  }
}

// ---------------------------------------------------------------------------
extern "C" void kernel_launch(void* const* d_in, const int* in_sizes, int n_in,
                              void* d_out, int out_size, void* d_ws, size_t ws_size,
                              hipStream_t stream) {
  const float* x    = (const float*)d_in[0];
  const int*   mask = (const int*)  d_in[1];
  const float* w1   = (const float*)d_in[2];
  const float* g1   = (const float*)d_in[3];
  const float* b1   = (const float*)d_in[4];
  const float* w2   = (const float*)d_in[5];
  const float* g2   = (const float*)d_in[6];
  const float* b2   = (const float*)d_in[7];
  const float* wqk  = (const float*)d_in[8];
  const float* wv   = (const float*)d_in[9];
  const float* bv   = (const float*)d_in[10];
  const float* wt   = (const float*)d_in[11];
  const float* bt   = (const float*)d_in[12];
  const float* sg   = (const float*)d_in[13];
  const float* sb   = (const float*)d_in[14];
  float* out = (float*)d_out;

  char* p = (char*)d_ws;
  auto alloc = [&](size_t bytes) { char* r = p; p += (bytes + 255) & ~(size_t)255; return r; };
  float*    H      = (float*)   alloc((size_t)B * C * N * 4);
  float*    T2     = (float*)   alloc((size_t)B * C * N * 4);
  float*    Td     = (float*)   alloc((size_t)B * C * N * 4);
  _Float16* XQKT   = (_Float16*)alloc((size_t)B * N * 32 * 2);
  _Float16* XV     = (_Float16*)alloc((size_t)B * C * N * 2);
  float*    rowmax = (float*)   alloc((size_t)B * N * 4);
  float*    rowsi  = (float*)   alloc((size_t)B * N * 4);
  float*    ss     = (float*)   alloc((size_t)C * 2 * 4);
  (void)ws_size;

  // ---- stem: two conv1d(+BN+ReLU) ----
  k_gw<false, false><<<dim3(64, 2, B), 256, 0, stream>>>(w1, x, nullptr, T2);
  k_bnstats<<<C, 256, 0, stream>>>(T2, g1, b1, ss);
  k_apply<false><<<2048, 256, 0, stream>>>(T2, ss, H, nullptr);
  k_gw<false, false><<<dim3(64, 2, B), 256, 0, stream>>>(w2, H, nullptr, T2);
  k_bnstats<<<C, 256, 0, stream>>>(T2, g2, b2, ss);
  k_apply<false><<<2048, 256, 0, stream>>>(T2, ss, H, nullptr);

  // ---- 4 chained offset-attention layers (flash-style, no E buffer) ----
  for (int L = 0; L < 4; L++) {
    k_qkt<<<dim3(64, 1, B), 256, 0, stream>>>(wqk + (size_t)L * 32 * C, H, XQKT);
    k_gw<true, true><<<dim3(64, 2, B), 256, 0, stream>>>(wv + (size_t)L * C * C, H, bv + L * C, XV);
    k_sm<<<dim3(64, B), 512, 0, stream>>>(XQKT, mask, rowmax, rowsi);
    k_pv<<<dim3(128, B), 512, 0, stream>>>(XQKT, XV, H, mask, rowmax, rowsi, Td);
    k_gw<true, false><<<dim3(64, 2, B), 256, 0, stream>>>(wt + (size_t)L * C * C, Td, bt + L * C, T2);
    k_bnstats<<<C, 256, 0, stream>>>(T2, sg + L * C, sb + L * C, ss);
    k_apply<true><<<2048, 256, 0, stream>>>(T2, ss, H, out + (size_t)L * C * N);
  }
}